// Round 1
// baseline (2866.974 us; speedup 1.0000x reference)
//
#include <hip/hip_runtime.h>

#define NTHREADS 512
#define TSEQ 512

__device__ __forceinline__ float sigmoid_(float x) {
    return 1.0f / (1.0f + __expf(-x));
}
__device__ __forceinline__ float tanh_(float x) {
    // tanh(x) = 1 - 2/(exp(2x)+1); stable at +/-inf via exp saturation
    return 1.0f - 2.0f / (1.0f + __expf(2.0f * x));
}

// One LSTM layer for batch element b, executed by one 512-thread workgroup.
// Thread (u = tid&127, kg = tid>>2bits): owns gates {i,f,g,o} of unit u over
// k-chunk [CHUNK*kg, CHUNK*kg+CHUNK) of the combined [x_t ; h_t] vector.
// Weights live in registers (w[4][CHUNK]); x/h broadcast via LDS xh[];
// partial dot-products reduced via LDS part[].
template <int IN_L, int CHUNK, bool FIRST, bool STORE>
__device__ void run_layer(const float* __restrict__ Wih, const float* __restrict__ Whh,
                          const float* __restrict__ bL,
                          const float* xsrc,   // FIRST: x [B,T,5]; else h_seq [B,T,100]
                          float* hdst,         // h_seq out [B,T,100] (may alias xsrc)
                          int b, int tid, int u, int kg,
                          float* xh, float4* part,
                          float* sb_ih, float* sb_hh) {
    float w[4][CHUNK];
    float bias[4];

    // ---- stage weights: global -> LDS (coalesced) -> registers, per gate type ----
#pragma unroll
    for (int g = 0; g < 4; ++g) {
        {
            const float4* s1 = (const float4*)(Wih + g * 100 * IN_L);
            float4* d1 = (float4*)sb_ih;
            for (int i = tid; i < (100 * IN_L) / 4; i += NTHREADS) d1[i] = s1[i];
            const float4* s2 = (const float4*)(Whh + g * 100 * 100);
            float4* d2 = (float4*)sb_hh;
            for (int i = tid; i < 2500; i += NTHREADS) d2[i] = s2[i];
        }
        __syncthreads();
#pragma unroll
        for (int kk = 0; kk < CHUNK; ++kk) {
            int k = CHUNK * kg + kk;
            float v = 0.0f;
            if (u < 100) {
                if (k < IN_L) v = sb_ih[u * IN_L + k];
                else if (k < IN_L + 100) v = sb_hh[u * 100 + (k - IN_L)];
            }
            w[g][kk] = v;
        }
        bias[g] = (u < 100) ? bL[g * 100 + u] : 0.0f;
        __syncthreads();  // before sb reuse for next gate type
    }

    // ---- init state & t=0 input ----
    float c = 0.0f;
    for (int i = tid; i < 4 * CHUNK; i += NTHREADS) xh[i] = 0.0f;
    __syncthreads();
    if (FIRST) {
        if (tid < IN_L) xh[tid] = xsrc[(b * TSEQ) * IN_L + tid];
    } else {
        if (tid < 25) ((float4*)xh)[tid] = ((const float4*)xsrc)[(b * TSEQ) * 25 + tid];
    }
    __syncthreads();

    const float4* xv4 = (const float4*)(xh + CHUNK * kg);  // CHUNK*4 bytes is 16B-aligned

    // ---- time loop ----
    for (int t = 0; t < TSEQ; ++t) {
        float p0 = 0.f, p1 = 0.f, p2 = 0.f, p3 = 0.f;
#pragma unroll
        for (int kv = 0; kv < CHUNK / 4; ++kv) {
            float4 xv = xv4[kv];
            p0 = fmaf(w[0][4 * kv + 0], xv.x, p0);
            p0 = fmaf(w[0][4 * kv + 1], xv.y, p0);
            p0 = fmaf(w[0][4 * kv + 2], xv.z, p0);
            p0 = fmaf(w[0][4 * kv + 3], xv.w, p0);
            p1 = fmaf(w[1][4 * kv + 0], xv.x, p1);
            p1 = fmaf(w[1][4 * kv + 1], xv.y, p1);
            p1 = fmaf(w[1][4 * kv + 2], xv.z, p1);
            p1 = fmaf(w[1][4 * kv + 3], xv.w, p1);
            p2 = fmaf(w[2][4 * kv + 0], xv.x, p2);
            p2 = fmaf(w[2][4 * kv + 1], xv.y, p2);
            p2 = fmaf(w[2][4 * kv + 2], xv.z, p2);
            p2 = fmaf(w[2][4 * kv + 3], xv.w, p2);
            p3 = fmaf(w[3][4 * kv + 0], xv.x, p3);
            p3 = fmaf(w[3][4 * kv + 1], xv.y, p3);
            p3 = fmaf(w[3][4 * kv + 2], xv.z, p3);
            p3 = fmaf(w[3][4 * kv + 3], xv.w, p3);
        }
        part[kg * 128 + u] = make_float4(p0, p1, p2, p3);

        // prefetch next step's x-part (latency hidden behind barrier + reduce)
        int tn = (t + 1 < TSEQ) ? (t + 1) : (TSEQ - 1);
        float4 pfv = make_float4(0.f, 0.f, 0.f, 0.f);
        float pfs = 0.f;
        if (FIRST) {
            if (kg == 1 && u < IN_L) pfs = xsrc[(b * TSEQ + tn) * IN_L + u];
        } else {
            if (kg == 1 && u < 25) pfv = ((const float4*)xsrc)[(b * TSEQ + tn) * 25 + u];
        }
        __syncthreads();

        // reduce partials across kg, activations, state update (replicated over kg)
        float4 q0 = part[u];
        float4 q1 = part[128 + u];
        float4 q2 = part[256 + u];
        float4 q3 = part[384 + u];
        float gi = sigmoid_(q0.x + q1.x + q2.x + q3.x + bias[0]);
        float gf = sigmoid_(q0.y + q1.y + q2.y + q3.y + bias[1]);
        float gn = tanh_   (q0.z + q1.z + q2.z + q3.z + bias[2]);
        float go = sigmoid_(q0.w + q1.w + q2.w + q3.w + bias[3]);
        c = gf * c + gi * gn;
        float h = go * tanh_(c);
        if (kg == 0 && u < 100) {
            xh[IN_L + u] = h;
            if (STORE) hdst[(b * TSEQ + t) * 100 + u] = h;
        }
        if (FIRST) {
            if (kg == 1 && u < IN_L) xh[u] = pfs;
        } else {
            if (kg == 1 && u < 25) ((float4*)xh)[u] = pfv;
        }
        __syncthreads();
    }
}

// y[j] = act(b[j] + sum_k in[k]*W[j,k]), j < J (J<=128), k < 100.
template <bool RELU, bool TOGLOBAL>
__device__ void fc_layer(const float* __restrict__ W, const float* __restrict__ bv, int J,
                         const float* inp, float* outp, float* outg, int b,
                         int tid, int u, int kg, float4* part, float* sb) {
    int n4 = J * 25;
    const float4* s = (const float4*)W;
    float4* d = (float4*)sb;
    for (int i = tid; i < n4; i += NTHREADS) d[i] = s[i];
    __syncthreads();
    float p = 0.f;
    if (u < J) {
#pragma unroll
        for (int kk = 0; kk < 25; ++kk)
            p = fmaf(sb[u * 100 + 25 * kg + kk], inp[25 * kg + kk], p);
    }
    part[kg * 128 + u].x = p;
    __syncthreads();
    if (kg == 0 && u < J) {
        float sacc = part[u].x + part[128 + u].x + part[256 + u].x + part[384 + u].x + bv[u];
        if (RELU) sacc = fmaxf(sacc, 0.f);
        if (TOGLOBAL) outg[b * 3 + u] = sacc;
        else outp[u] = sacc;
    }
    __syncthreads();
}

extern "C" __global__ void __launch_bounds__(NTHREADS, 2)
gesture_lstm_kernel(const float* __restrict__ x,
                    const float* __restrict__ Wih0, const float* __restrict__ Whh0,
                    const float* __restrict__ b0,
                    const float* __restrict__ WihL, const float* __restrict__ WhhL,
                    const float* __restrict__ bLv,
                    const float* __restrict__ gamma, const float* __restrict__ beta,
                    const float* __restrict__ rmean, const float* __restrict__ rvar,
                    const float* __restrict__ W1, const float* __restrict__ b1,
                    const float* __restrict__ W2, const float* __restrict__ b2,
                    const float* __restrict__ W3, const float* __restrict__ b3,
                    float* __restrict__ out, float* hseq) {
    __shared__ __align__(16) float xh[208];
    __shared__ float4 part[512];
    __shared__ __align__(16) float sb_ih[10000];
    __shared__ __align__(16) float sb_hh[10000];

    int tid = threadIdx.x;
    int u = tid & 127;
    int kg = tid >> 7;
    int b = blockIdx.x;

    // LSTM stack: one workgroup handles batch element b end-to-end.
    run_layer<5, 28, true, true>(Wih0, Whh0, b0, x, hseq, b, tid, u, kg, xh, part, sb_ih, sb_hh);
    run_layer<100, 52, false, true>(WihL + 0,      WhhL + 0,      bLv + 0,    hseq, hseq, b, tid, u, kg, xh, part, sb_ih, sb_hh);
    run_layer<100, 52, false, true>(WihL + 40000,  WhhL + 40000,  bLv + 400,  hseq, hseq, b, tid, u, kg, xh, part, sb_ih, sb_hh);
    run_layer<100, 52, false, true>(WihL + 80000,  WhhL + 80000,  bLv + 800,  hseq, hseq, b, tid, u, kg, xh, part, sb_ih, sb_hh);
    run_layer<100, 52, false, false>(WihL + 120000, WhhL + 120000, bLv + 1200, hseq, hseq, b, tid, u, kg, xh, part, sb_ih, sb_hh);

    // Head: BN (inference) -> FC1+ReLU -> FC2+ReLU -> FC3
    // xh[100..200) holds h_{T-1}; write xn into xh[0..100) (disjoint).
    if (kg == 0 && u < 100) {
        float h = xh[100 + u];
        float xn = (h - rmean[u]) * rsqrtf(rvar[u] + 1e-5f) * gamma[u] + beta[u];
        xh[u] = xn;
    }
    __syncthreads();
    fc_layer<true, false>(W1, b1, 100, xh, xh + 100, nullptr, b, tid, u, kg, part, sb_hh);
    fc_layer<true, false>(W2, b2, 100, xh + 100, xh, nullptr, b, tid, u, kg, part, sb_hh);
    fc_layer<false, true>(W3, b3, 3, xh, nullptr, out, b, tid, u, kg, part, sb_hh);
}

extern "C" void kernel_launch(void* const* d_in, const int* in_sizes, int n_in,
                              void* d_out, int out_size, void* d_ws, size_t ws_size,
                              hipStream_t stream) {
    const float* x     = (const float*)d_in[0];
    const float* Wih0  = (const float*)d_in[1];
    const float* Whh0  = (const float*)d_in[2];
    const float* b0    = (const float*)d_in[3];
    const float* WihL  = (const float*)d_in[4];
    const float* WhhL  = (const float*)d_in[5];
    const float* bLv   = (const float*)d_in[6];
    const float* gamma = (const float*)d_in[7];
    const float* beta  = (const float*)d_in[8];
    const float* rmean = (const float*)d_in[9];
    const float* rvar  = (const float*)d_in[10];
    const float* W1    = (const float*)d_in[11];
    const float* b1    = (const float*)d_in[12];
    const float* W2    = (const float*)d_in[13];
    const float* b2    = (const float*)d_in[14];
    const float* W3    = (const float*)d_in[15];
    const float* b3    = (const float*)d_in[16];

    float* hseq = (float*)d_ws;  // 256*512*100 fp32 = 52.4 MB, single in-place buffer

    gesture_lstm_kernel<<<dim3(256), dim3(NTHREADS), 0, stream>>>(
        x, Wih0, Whh0, b0, WihL, WhhL, bLv,
        gamma, beta, rmean, rvar, W1, b1, W2, b2, W3, b3,
        (float*)d_out, hseq);
}